// Round 12
// baseline (475.168 us; speedup 1.0000x reference)
//
#include <hip/hip_runtime.h>
#include <math.h>

#define BN_EPS 1e-5f

using bf16x8 = __attribute__((ext_vector_type(8))) short;
using f32x4  = __attribute__((ext_vector_type(4))) float;

// ---------------- bf16 helpers (RNE) ----------------

__device__ __forceinline__ float bf2f(unsigned short u) {
    union { unsigned int i; float f; } v; v.i = ((unsigned int)u) << 16; return v.f;
}
__device__ __forceinline__ unsigned short f2bf(float f) {
    union { float f; unsigned int i; } v; v.f = f;
    unsigned int lsb = (v.i >> 16) & 1u;
    v.i += 0x7fffu + lsb;
    return (unsigned short)(v.i >> 16);
}
__device__ __forceinline__ unsigned int pack2bf(float a, float b) {
    return (unsigned int)f2bf(a) | ((unsigned int)f2bf(b) << 16);
}

// ---------------- CSR build ----------------

__global__ void count_kernel(const int* __restrict__ dstv, int* __restrict__ cnt, int E) {
    int e = blockIdx.x * blockDim.x + threadIdx.x;
    if (e < E) atomicAdd(&cnt[dstv[e]], 1);
}

// block scan + dinv (fused)
__global__ void scan_block_kernel(const int* __restrict__ cnt, int* __restrict__ out,
                                  int* __restrict__ bsum, float* __restrict__ dinv, int Nn) {
    __shared__ int s[256];
    int t = threadIdx.x;
    int i = blockIdx.x * 256 + t;
    int v = (i < Nn) ? cnt[i] : 0;
    if (i < Nn) dinv[i] = rsqrtf((float)v + 1.0f);  // +1 self-loop
    s[t] = v;
    __syncthreads();
    for (int off = 1; off < 256; off <<= 1) {
        int add = (t >= off) ? s[t - off] : 0;
        __syncthreads();
        s[t] += add;
        __syncthreads();
    }
    if (i < Nn) out[i] = s[t] - v;
    if (t == 255) bsum[blockIdx.x] = s[255];
}

__global__ void scan_sums_kernel(int* __restrict__ bsum, int nb) {
    __shared__ int s[512];
    int t = threadIdx.x;
    int v = (t < nb) ? bsum[t] : 0;
    s[t] = v;
    __syncthreads();
    for (int off = 1; off < 512; off <<= 1) {
        int add = (t >= off) ? s[t - off] : 0;
        __syncthreads();
        s[t] += add;
        __syncthreads();
    }
    if (t < nb) bsum[t] = s[t] - v;
}

// add block offsets, init pos, AND graph boundaries (fused)
__global__ void add_offsets_kernel(int* __restrict__ row_ptr, const int* __restrict__ bsum,
                                   int* __restrict__ pos,
                                   const int* __restrict__ batch, int* __restrict__ start,
                                   int Nn, int E, int G) {
    int i = blockIdx.x * 256 + threadIdx.x;
    if (i < Nn) {
        int v = row_ptr[i] + bsum[blockIdx.x];
        row_ptr[i] = v;
        pos[i] = v;
        int b = batch[i];
        if (i == 0) {
            for (int g = 0; g <= b; ++g) start[g] = 0;
        } else {
            int p = batch[i - 1];
            for (int g = p + 1; g <= b; ++g) start[g] = i;
        }
        if (i == Nn - 1) {
            for (int g = b + 1; g <= G; ++g) start[g] = Nn;
        }
    }
    if (i == 0) row_ptr[Nn] = E;
}

__global__ void cursor_init_kernel(const int* __restrict__ row_ptr, int* __restrict__ cur, int Nn) {
    int b = threadIdx.x;
    if (b < 8) cur[b] = row_ptr[(int)(((long long)b * Nn) >> 3)];
}

// ---- Phase A: bucket edges by dst-eighth; block-contiguous appends (full-line writes)
// entry: x = src | (dstLocal<<17)   (src<2^17, dstLocal<2^14), y = f32 bits of dinv[src]

__global__ __launch_bounds__(256)
void bucket_kernel(const int* __restrict__ srcv, const int* __restrict__ dstv,
                   const float* __restrict__ dinv,
                   int* __restrict__ bucketCursor, int2* __restrict__ bkt, int E, int Nn) {
    __shared__ int hist[8], base[8], lcur[8];
    int tid = threadIdx.x;
    if (tid < 8) { hist[tid] = 0; lcur[tid] = 0; }
    __syncthreads();
    int e0 = blockIdx.x * 2048;

    int pk[8]; float wv[8]; int bb[8]; bool val[8];
    #pragma unroll
    for (int u = 0; u < 8; ++u) {
        int e = e0 + u * 256 + tid;
        val[u] = (e < E);
        if (val[u]) {
            int d = dstv[e];
            int s = srcv[e];
            wv[u] = dinv[s];
            int b = (int)(((long long)d * 8) / Nn);
            int lo = (int)(((long long)b * Nn) >> 3);
            bb[u] = b;
            pk[u] = s | ((d - lo) << 17);
            atomicAdd(&hist[b], 1);
        }
    }
    __syncthreads();
    if (tid < 8) base[tid] = atomicAdd(&bucketCursor[tid], hist[tid]);
    __syncthreads();
    #pragma unroll
    for (int u = 0; u < 8; ++u) {
        if (val[u]) {
            int slot = atomicAdd(&lcur[bb[u]], 1);
            bkt[base[bb[u]] + slot] = make_int2(pk[u], __float_as_int(wv[u]));
        }
    }
}

// ---- Phase B: per-XCD dst-slice scatter; working set (bucket seg + cw slice + pos) fits L2

__global__ __launch_bounds__(256)
void scatter2_kernel(const int2* __restrict__ bkt, const int* __restrict__ row_ptr,
                     int* __restrict__ pos, int2* __restrict__ cw, int Nn) {
    int part = blockIdx.x & 7;
    int bidx = blockIdx.x >> 3;
    int nb   = gridDim.x >> 3;
    int lo = (int)(((long long)part * Nn) >> 3);
    int hi = (int)(((long long)(part + 1) * Nn) >> 3);
    int s0 = row_ptr[lo];
    int s1 = row_ptr[hi];
    for (int i = s0 + bidx * 256 + threadIdx.x; i < s1; i += nb * 256) {
        int2 en = bkt[i];
        int src = en.x & 0x1ffff;
        int d = lo + (int)(((unsigned int)en.x) >> 17);
        int p = atomicAdd(&pos[d], 1);
        cw[p] = make_int2(src, en.y);
    }
}

// ---------------- weight f32 -> bf16 conversion ----------------

__global__ void convw_kernel(const float* __restrict__ W1, const float* __restrict__ W2,
                             const float* __restrict__ W3,
                             unsigned short* __restrict__ w1b, unsigned short* __restrict__ w2b,
                             unsigned short* __restrict__ w3b) {
    int i = blockIdx.x * 256 + threadIdx.x;
    if (i < 128 * 128) w1b[i] = f2bf(W1[i]);
    if (i < 128 * 64)  w2b[i] = f2bf(W2[i]);
    if (i < 64 * 64)   w3b[i] = f2bf(W3[i]);
}

// ---------------- MFMA GEMM: C[M,N](bf16) = A[M,K](f32|bf16) @ Wb[K,N](bf16) ----------------

template<int K, int N, bool AF32>
__global__ __launch_bounds__(256)
void gemm_mfma(const void* __restrict__ Ap, const unsigned short* __restrict__ Wb,
               unsigned short* __restrict__ C, int M) {
    constexpr int KF = K / 32;
    constexpr int NF = N / 16;
    __shared__ __align__(16) unsigned short ldsW[KF * NF * 64 * 8];

    for (int c = threadIdx.x; c < K * N / 8; c += 256) {
        int e0 = c * 8;
        int k = e0 / N, n0 = e0 % N;
        uint4 v = *(const uint4*)&Wb[e0];
        unsigned short w[8];
        w[0] = (unsigned short)(v.x & 0xffff); w[1] = (unsigned short)(v.x >> 16);
        w[2] = (unsigned short)(v.y & 0xffff); w[3] = (unsigned short)(v.y >> 16);
        w[4] = (unsigned short)(v.z & 0xffff); w[5] = (unsigned short)(v.z >> 16);
        w[6] = (unsigned short)(v.w & 0xffff); w[7] = (unsigned short)(v.w >> 16);
        int j    = k & 7;
        int lhi  = ((k & 31) >> 3) << 4;
        int fbase = (k >> 5) * NF;
        #pragma unroll
        for (int u = 0; u < 8; ++u) {
            int n = n0 + u;
            int f = fbase + (n >> 4);
            int l = lhi | (n & 15);
            ldsW[(f * 64 + l) * 8 + j] = w[u];
        }
    }
    __syncthreads();

    const int wave = threadIdx.x >> 6;
    const int lane = threadIdx.x & 63;
    const int r0   = blockIdx.x * 64 + wave * 16;

    int arow = r0 + (lane & 15);
    if (arow >= M) arow = M - 1;
    const int kc0 = (lane >> 4) * 8;
    bf16x8 af[KF];
    #pragma unroll
    for (int k = 0; k < KF; ++k) {
        if constexpr (AF32) {
            const float* A = (const float*)Ap;
            const float4* p = (const float4*)&A[(size_t)arow * K + k * 32 + kc0];
            float4 u0 = p[0], u1 = p[1];
            unsigned int q0 = pack2bf(u0.x, u0.y), q1 = pack2bf(u0.z, u0.w);
            unsigned int q2 = pack2bf(u1.x, u1.y), q3 = pack2bf(u1.z, u1.w);
            bf16x8 a;
            a[0] = (short)(q0 & 0xffff); a[1] = (short)(q0 >> 16);
            a[2] = (short)(q1 & 0xffff); a[3] = (short)(q1 >> 16);
            a[4] = (short)(q2 & 0xffff); a[5] = (short)(q2 >> 16);
            a[6] = (short)(q3 & 0xffff); a[7] = (short)(q3 >> 16);
            af[k] = a;
        } else {
            const unsigned short* A = (const unsigned short*)Ap;
            af[k] = *(const bf16x8*)&A[(size_t)arow * K + k * 32 + kc0];
        }
    }

    const int colb = lane & 15;
    const int rsub = (lane >> 4) * 4;
    #pragma unroll
    for (int n = 0; n < NF; ++n) {
        f32x4 acc = {0.f, 0.f, 0.f, 0.f};
        #pragma unroll
        for (int k = 0; k < KF; ++k) {
            bf16x8 bf = *(const bf16x8*)&ldsW[((k * NF + n) * 64 + lane) * 8];
            acc = __builtin_amdgcn_mfma_f32_16x16x32_bf16(af[k], bf, acc, 0, 0, 0);
        }
        int col = n * 16 + colb;
        #pragma unroll
        for (int j = 0; j < 4; ++j) {
            int row = r0 + rsub + j;
            if (row < M) C[(size_t)row * N + col] = f2bf(acc[j]);
        }
    }
}

// ---------------- fused gather + self-loop + bias + BN + ReLU (bf16 in/out) ----------------

__global__ __launch_bounds__(256)
void gcn_gather128(const unsigned short* __restrict__ t, unsigned short* __restrict__ out,
                   const int* __restrict__ row_ptr, const int2* __restrict__ cw,
                   const float* __restrict__ dinv,
                   const float* __restrict__ bias,
                   const float* __restrict__ gam, const float* __restrict__ bet,
                   const float* __restrict__ mu,  const float* __restrict__ var,
                   int Nn) {
    int node = (int)((blockIdx.x * 256 + threadIdx.x) >> 6);
    int lane = threadIdx.x & 63;
    if (node >= Nn) return;

    int b0 = row_ptr[node];
    int b1 = row_ptr[node + 1];
    float di = dinv[node];
    const unsigned int* tu = (const unsigned int*)t;

    float acc0 = 0.0f, acc1 = 0.0f;
    int e = b0;
    for (; e + 16 <= b1; e += 16) {
        int2 c16[16];
        unsigned int f[16];
        #pragma unroll
        for (int u = 0; u < 16; ++u) c16[u] = cw[e + u];
        #pragma unroll
        for (int u = 0; u < 16; ++u) f[u] = tu[(size_t)c16[u].x * 64 + lane];
        #pragma unroll
        for (int u = 0; u < 16; ++u) {
            float w = __int_as_float(c16[u].y);
            acc0 = fmaf(w, bf2f((unsigned short)(f[u] & 0xffff)), acc0);
            acc1 = fmaf(w, bf2f((unsigned short)(f[u] >> 16)),   acc1);
        }
    }
    for (; e + 4 <= b1; e += 4) {
        int2 c4[4];
        unsigned int f[4];
        #pragma unroll
        for (int u = 0; u < 4; ++u) c4[u] = cw[e + u];
        #pragma unroll
        for (int u = 0; u < 4; ++u) f[u] = tu[(size_t)c4[u].x * 64 + lane];
        #pragma unroll
        for (int u = 0; u < 4; ++u) {
            float w = __int_as_float(c4[u].y);
            acc0 = fmaf(w, bf2f((unsigned short)(f[u] & 0xffff)), acc0);
            acc1 = fmaf(w, bf2f((unsigned short)(f[u] >> 16)),   acc1);
        }
    }
    for (; e < b1; ++e) {
        int2 c = cw[e];
        unsigned int f = tu[(size_t)c.x * 64 + lane];
        float w = __int_as_float(c.y);
        acc0 = fmaf(w, bf2f((unsigned short)(f & 0xffff)), acc0);
        acc1 = fmaf(w, bf2f((unsigned short)(f >> 16)),   acc1);
    }

    float d2 = di * di;
    unsigned int tv = tu[(size_t)node * 64 + lane];
    int c0 = 2 * lane, c1 = 2 * lane + 1;
    float sc0 = gam[c0] * rsqrtf(var[c0] + BN_EPS);
    float sc1 = gam[c1] * rsqrtf(var[c1] + BN_EPS);
    float sh0 = bet[c0] - mu[c0] * sc0;
    float sh1 = bet[c1] - mu[c1] * sc1;
    float h0 = di * acc0 + d2 * bf2f((unsigned short)(tv & 0xffff)) + bias[c0];
    float h1 = di * acc1 + d2 * bf2f((unsigned short)(tv >> 16))   + bias[c1];
    float o0 = fmaxf(h0 * sc0 + sh0, 0.0f);
    float o1 = fmaxf(h1 * sc1 + sh1, 0.0f);
    ((unsigned int*)out)[(size_t)node * 64 + lane] = pack2bf(o0, o1);
}

__global__ __launch_bounds__(256)
void gcn_gather64(const unsigned short* __restrict__ t, unsigned short* __restrict__ out,
                  const int* __restrict__ row_ptr, const int2* __restrict__ cw,
                  const float* __restrict__ dinv,
                  const float* __restrict__ bias,
                  const float* __restrict__ gam, const float* __restrict__ bet,
                  const float* __restrict__ mu,  const float* __restrict__ var,
                  int Nn) {
    int node = (int)((blockIdx.x * 256 + threadIdx.x) >> 6);
    int lane = threadIdx.x & 63;
    if (node >= Nn) return;

    int b0 = row_ptr[node];
    int b1 = row_ptr[node + 1];
    float di = dinv[node];

    float acc = 0.0f;
    int e = b0;
    for (; e + 16 <= b1; e += 16) {
        int2 c16[16];
        unsigned short f[16];
        #pragma unroll
        for (int u = 0; u < 16; ++u) c16[u] = cw[e + u];
        #pragma unroll
        for (int u = 0; u < 16; ++u) f[u] = t[(size_t)c16[u].x * 64 + lane];
        #pragma unroll
        for (int u = 0; u < 16; ++u)
            acc = fmaf(__int_as_float(c16[u].y), bf2f(f[u]), acc);
    }
    for (; e + 4 <= b1; e += 4) {
        int2 c4[4];
        unsigned short f[4];
        #pragma unroll
        for (int u = 0; u < 4; ++u) c4[u] = cw[e + u];
        #pragma unroll
        for (int u = 0; u < 4; ++u) f[u] = t[(size_t)c4[u].x * 64 + lane];
        #pragma unroll
        for (int u = 0; u < 4; ++u)
            acc = fmaf(__int_as_float(c4[u].y), bf2f(f[u]), acc);
    }
    for (; e < b1; ++e) {
        int2 c = cw[e];
        acc = fmaf(__int_as_float(c.y), bf2f(t[(size_t)c.x * 64 + lane]), acc);
    }

    float d2 = di * di;
    float tv = bf2f(t[(size_t)node * 64 + lane]);
    int c = lane;
    float sc = gam[c] * rsqrtf(var[c] + BN_EPS);
    float sh = bet[c] - mu[c] * sc;
    float h  = di * acc + d2 * tv + bias[c];
    out[(size_t)node * 64 + lane] = f2bf(fmaxf(h * sc + sh, 0.0f));
}

// ---------------- parallel pool: wave per 64-node chunk, lane = channel ----------------

__global__ __launch_bounds__(256)
void pool_sum_kernel(const unsigned short* __restrict__ h3, const int* __restrict__ batch,
                     float* __restrict__ sums, int Nn) {
    int wid  = (int)((blockIdx.x * 256 + threadIdx.x) >> 6);
    int lane = threadIdx.x & 63;
    int i0 = wid * 64;
    if (i0 >= Nn) return;
    int i1 = i0 + 64; if (i1 > Nn) i1 = Nn;

    float acc = 0.0f;
    int g = batch[i0];
    for (int i = i0; i < i1; ++i) {
        int gi = batch[i];
        if (gi != g) {
            unsafeAtomicAdd(&sums[g * 64 + lane], acc);
            acc = 0.0f;
            g = gi;
        }
        acc += bf2f(h3[(size_t)i * 64 + lane]);
    }
    unsafeAtomicAdd(&sums[g * 64 + lane], acc);
}

// ---------------- MLP head on pooled sums ----------------

__global__ __launch_bounds__(64)
void mlp_kernel(const float* __restrict__ sums, const int* __restrict__ start,
                const float* __restrict__ Wm1, const float* __restrict__ bm1,
                const float* __restrict__ Wm2, const float* __restrict__ bm2,
                float* __restrict__ out) {
    int g = blockIdx.x;
    int c = threadIdx.x;  // 64
    float cnt = (float)(start[g + 1] - start[g]);
    float pooled = sums[g * 64 + c] / fmaxf(cnt, 1.0f);
    __shared__ float pl[64];
    __shared__ float zl[64];
    pl[c] = pooled;
    __syncthreads();
    float z = bm1[c];
    for (int j = 0; j < 64; ++j) z = fmaf(pl[j], Wm1[j * 64 + c], z);
    z = fmaxf(z, 0.0f);
    zl[c] = z;
    __syncthreads();
    if (c < 10) {
        float o = bm2[c];
        for (int j = 0; j < 64; ++j) o = fmaf(zl[j], Wm2[j * 10 + c], o);
        out[g * 10 + c] = o;
    }
}

// ---------------- launcher ----------------

static inline int cdiv(int a, int b) { return (a + b - 1) / b; }

extern "C" void kernel_launch(void* const* d_in, const int* in_sizes, int n_in,
                              void* d_out, int out_size, void* d_ws, size_t ws_size,
                              hipStream_t stream) {
    const float* x   = (const float*)d_in[0];
    const int* edge  = (const int*)d_in[1];
    const int* batch = (const int*)d_in[2];
    const float* W1  = (const float*)d_in[3];
    const float* b1  = (const float*)d_in[4];
    const float* W2  = (const float*)d_in[5];
    const float* b2  = (const float*)d_in[6];
    const float* W3  = (const float*)d_in[7];
    const float* b3  = (const float*)d_in[8];
    const float* g1  = (const float*)d_in[9];
    const float* be1 = (const float*)d_in[10];
    const float* m1  = (const float*)d_in[11];
    const float* v1  = (const float*)d_in[12];
    const float* g2  = (const float*)d_in[13];
    const float* be2 = (const float*)d_in[14];
    const float* m2  = (const float*)d_in[15];
    const float* v2  = (const float*)d_in[16];
    const float* g3  = (const float*)d_in[17];
    const float* be3 = (const float*)d_in[18];
    const float* m3  = (const float*)d_in[19];
    const float* v3  = (const float*)d_in[20];
    const float* Wm1 = (const float*)d_in[21];
    const float* bm1 = (const float*)d_in[22];
    const float* Wm2 = (const float*)d_in[23];
    const float* bm2 = (const float*)d_in[24];
    float* outp = (float*)d_out;

    const int Nn = in_sizes[0] / 128;
    const int E  = in_sizes[1] / 2;
    const int G  = 128;
    const int* srcv = edge;
    const int* dstv = edge + E;

    // ws layout (bytes):
    // bufA (Nn*128 bf16) | bufB (Nn*128 bf16) | dinv (Nn f32) | cw (E int2) | bkt (E int2)
    // | row_ptr (Nn+1 int) | start (G+1 int) | sums (G*64 f32) | bucketCursor(8) | w1b/w2b/w3b
    char* wsb = (char*)d_ws;
    unsigned short* bufA = (unsigned short*)wsb;
    unsigned short* bufB = bufA + (size_t)Nn * 128;
    float* dinv    = (float*)(bufB + (size_t)Nn * 128);
    int2*  cw      = (int2*)(dinv + Nn);
    int2*  bkt     = cw + E;
    int*   row_ptr = (int*)(bkt + E);
    int*   start   = row_ptr + (Nn + 1);
    float* sums    = (float*)(start + (G + 1));
    int*   bucketCursor = (int*)(sums + G * 64);
    unsigned short* w1b = (unsigned short*)(bucketCursor + 8);
    unsigned short* w2b = w1b + 128 * 128;
    unsigned short* w3b = w2b + 128 * 64;

    // transient ints overlaid on bufA (free until GEMM1 writes it)
    int* cnt  = (int*)bufA;            // Nn
    int* pos  = cnt + Nn;              // Nn
    int* bsum = pos + Nn;              // cdiv(Nn,256)

    const int TB = 256;
    const int nb = cdiv(Nn, 256);

    // ---- CSR build + norms + weight conversion + graph boundaries ----
    hipMemsetAsync(cnt, 0, (size_t)Nn * sizeof(int), stream);
    count_kernel<<<cdiv(E, TB), TB, 0, stream>>>(dstv, cnt, E);
    scan_block_kernel<<<nb, 256, 0, stream>>>(cnt, row_ptr, bsum, dinv, Nn);
    scan_sums_kernel<<<1, 512, 0, stream>>>(bsum, nb);
    add_offsets_kernel<<<nb, 256, 0, stream>>>(row_ptr, bsum, pos, batch, start, Nn, E, G);
    cursor_init_kernel<<<1, 8, 0, stream>>>(row_ptr, bucketCursor, Nn);
    bucket_kernel<<<cdiv(E, 2048), 256, 0, stream>>>(srcv, dstv, dinv, bucketCursor, bkt, E, Nn);
    scatter2_kernel<<<2048, 256, 0, stream>>>(bkt, row_ptr, pos, cw, Nn);
    convw_kernel<<<64, 256, 0, stream>>>(W1, W2, W3, w1b, w2b, w3b);

    // ---- layer 1: t = x @ W1 (128->128, f32 A -> bf16); gather -> bufB ----
    gemm_mfma<128, 128, true><<<cdiv(Nn, 64), 256, 0, stream>>>(x, w1b, bufA, Nn);
    gcn_gather128<<<cdiv(Nn, 4), 256, 0, stream>>>(bufA, bufB, row_ptr, cw, dinv,
                                                   b1, g1, be1, m1, v1, Nn);

    // ---- layer 2: t = h1 @ W2 (128->64) ----
    gemm_mfma<128, 64, false><<<cdiv(Nn, 64), 256, 0, stream>>>(bufB, w2b, bufA, Nn);
    gcn_gather64<<<cdiv(Nn, 4), 256, 0, stream>>>(bufA, bufB, row_ptr, cw, dinv,
                                                  b2, g2, be2, m2, v2, Nn);

    // ---- layer 3: t = h2 @ W3 (64->64) ----
    gemm_mfma<64, 64, false><<<cdiv(Nn, 64), 256, 0, stream>>>(bufB, w3b, bufA, Nn);
    gcn_gather64<<<cdiv(Nn, 4), 256, 0, stream>>>(bufA, bufB, row_ptr, cw, dinv,
                                                  b3, g3, be3, m3, v3, Nn);

    // ---- pool + MLP ----
    hipMemsetAsync(sums, 0, (size_t)G * 64 * sizeof(float), stream);
    pool_sum_kernel<<<cdiv(Nn, 256), 256, 0, stream>>>(bufB, batch, sums, Nn);
    mlp_kernel<<<G, 64, 0, stream>>>(sums, start, Wm1, bm1, Wm2, bm2, outp);
}

// Round 13
// 439.496 us; speedup vs baseline: 1.0812x; 1.0812x over previous
//
#include <hip/hip_runtime.h>
#include <math.h>

#define BN_EPS 1e-5f

using bf16x8 = __attribute__((ext_vector_type(8))) short;
using f32x4  = __attribute__((ext_vector_type(4))) float;

// ---------------- bf16 helpers (RNE) ----------------

__device__ __forceinline__ float bf2f(unsigned short u) {
    union { unsigned int i; float f; } v; v.i = ((unsigned int)u) << 16; return v.f;
}
__device__ __forceinline__ unsigned short f2bf(float f) {
    union { float f; unsigned int i; } v; v.f = f;
    unsigned int lsb = (v.i >> 16) & 1u;
    v.i += 0x7fffu + lsb;
    return (unsigned short)(v.i >> 16);
}
__device__ __forceinline__ unsigned int pack2bf(float a, float b) {
    return (unsigned int)f2bf(a) | ((unsigned int)f2bf(b) << 16);
}

// ---------------- CSR build ----------------

__global__ void count_kernel(const int* __restrict__ dstv, int* __restrict__ cnt, int E) {
    int e = blockIdx.x * blockDim.x + threadIdx.x;
    if (e < E) atomicAdd(&cnt[dstv[e]], 1);
}

// block scan + dinv (fused)
__global__ void scan_block_kernel(const int* __restrict__ cnt, int* __restrict__ out,
                                  int* __restrict__ bsum, float* __restrict__ dinv, int Nn) {
    __shared__ int s[256];
    int t = threadIdx.x;
    int i = blockIdx.x * 256 + t;
    int v = (i < Nn) ? cnt[i] : 0;
    if (i < Nn) dinv[i] = rsqrtf((float)v + 1.0f);  // +1 self-loop
    s[t] = v;
    __syncthreads();
    for (int off = 1; off < 256; off <<= 1) {
        int add = (t >= off) ? s[t - off] : 0;
        __syncthreads();
        s[t] += add;
        __syncthreads();
    }
    if (i < Nn) out[i] = s[t] - v;
    if (t == 255) bsum[blockIdx.x] = s[255];
}

__global__ void scan_sums_kernel(int* __restrict__ bsum, int nb) {
    __shared__ int s[512];
    int t = threadIdx.x;
    int v = (t < nb) ? bsum[t] : 0;
    s[t] = v;
    __syncthreads();
    for (int off = 1; off < 512; off <<= 1) {
        int add = (t >= off) ? s[t - off] : 0;
        __syncthreads();
        s[t] += add;
        __syncthreads();
    }
    if (t < nb) bsum[t] = s[t] - v;
}

// add block offsets AND graph boundaries (fused)
__global__ void add_offsets_kernel(int* __restrict__ row_ptr, const int* __restrict__ bsum,
                                   const int* __restrict__ batch, int* __restrict__ start,
                                   int Nn, int E, int G) {
    int i = blockIdx.x * 256 + threadIdx.x;
    if (i < Nn) {
        int v = row_ptr[i] + bsum[blockIdx.x];
        row_ptr[i] = v;
        int b = batch[i];
        if (i == 0) {
            for (int g = 0; g <= b; ++g) start[g] = 0;
        } else {
            int p = batch[i - 1];
            for (int g = p + 1; g <= b; ++g) start[g] = i;
        }
        if (i == Nn - 1) {
            for (int g = b + 1; g <= G; ++g) start[g] = Nn;
        }
    }
    if (i == 0) row_ptr[Nn] = E;
}

// cursors: one per 512-node bucket, base = row_ptr[b*512]
__global__ void cursor_init_kernel(const int* __restrict__ row_ptr, int* __restrict__ cur, int Nn) {
    int b = threadIdx.x;  // 256
    int idx = b * 512; if (idx > Nn) idx = Nn;
    cur[b] = row_ptr[idx];
}

// ---- Phase A: bucket edges by 512-node dst range. Block-contiguous appends into
// bucket regions that coincide exactly with CSR segments (cursor base = row_ptr[lo]).
// entry: x = src | (dstLocal<<17)  (src<2^17, dstLocal<512), y = f32 bits dinv[src]

__global__ __launch_bounds__(256)
void bucketA_kernel(const int* __restrict__ srcv, const int* __restrict__ dstv,
                    const float* __restrict__ dinv,
                    int* __restrict__ cursor, int2* __restrict__ bkt, int E) {
    __shared__ int hist[256], base[256], lcur[256];
    __shared__ int2 stage[4096];
    int tid = threadIdx.x;
    hist[tid] = 0; lcur[tid] = 0;
    __syncthreads();
    int e0 = blockIdx.x * 4096;
    int nmax = E - e0; if (nmax > 4096) nmax = 4096;

    #pragma unroll
    for (int u = 0; u < 16; ++u) {
        int idx = u * 256 + tid;
        if (idx < nmax) {
            int e = e0 + idx;
            int d = dstv[e], s = srcv[e];
            stage[idx] = make_int2(d, s);
            atomicAdd(&hist[d >> 9], 1);
        }
    }
    __syncthreads();
    if (hist[tid] > 0) base[tid] = atomicAdd(&cursor[tid], hist[tid]);
    __syncthreads();
    #pragma unroll
    for (int u = 0; u < 16; ++u) {
        int idx = u * 256 + tid;
        if (idx < nmax) {
            int2 ds = stage[idx];
            int b = ds.x >> 9;
            int dl = ds.x & 511;
            int slot = atomicAdd(&lcur[b], 1);
            bkt[base[b] + slot] = make_int2(ds.y | (dl << 17), __float_as_int(dinv[ds.y]));
        }
    }
}

// ---- Phase B: one block per bucket; order its CSR segment in a block-local
// ~66 KB window (L2-resident for the block's lifetime, no XCD assumption).

__global__ __launch_bounds__(256)
void orderB_kernel(const int2* __restrict__ bkt, const int* __restrict__ row_ptr,
                   int2* __restrict__ cw, int Nn) {
    __shared__ int hist[512];
    __shared__ int scan_s[256];
    int b = blockIdx.x;
    int lo = b << 9;
    if (lo >= Nn) return;
    int hi = lo + 512; if (hi > Nn) hi = Nn;
    int s0 = row_ptr[lo], s1 = row_ptr[hi];
    int tid = threadIdx.x;
    hist[tid] = 0; hist[tid + 256] = 0;
    __syncthreads();
    for (int i = s0 + tid; i < s1; i += 256)
        atomicAdd(&hist[((unsigned int)bkt[i].x) >> 17], 1);
    __syncthreads();
    // exclusive scan of hist[512] (pairs -> Hillis-Steele over 256)
    int a0 = hist[2 * tid], a1 = hist[2 * tid + 1];
    int pairsum = a0 + a1;
    scan_s[tid] = pairsum;
    __syncthreads();
    for (int off = 1; off < 256; off <<= 1) {
        int add = (tid >= off) ? scan_s[tid - off] : 0;
        __syncthreads();
        scan_s[tid] += add;
        __syncthreads();
    }
    int excl = scan_s[tid] - pairsum;
    __syncthreads();
    hist[2 * tid] = excl;
    hist[2 * tid + 1] = excl + a0;
    __syncthreads();
    for (int i = s0 + tid; i < s1; i += 256) {
        int2 en = bkt[i];
        int dl = ((unsigned int)en.x) >> 17;
        int slot = atomicAdd(&hist[dl], 1);
        cw[s0 + slot] = make_int2(en.x & 0x1ffff, en.y);
    }
}

// ---------------- weight f32 -> bf16 conversion ----------------

__global__ void convw_kernel(const float* __restrict__ W1, const float* __restrict__ W2,
                             const float* __restrict__ W3,
                             unsigned short* __restrict__ w1b, unsigned short* __restrict__ w2b,
                             unsigned short* __restrict__ w3b) {
    int i = blockIdx.x * 256 + threadIdx.x;
    if (i < 128 * 128) w1b[i] = f2bf(W1[i]);
    if (i < 128 * 64)  w2b[i] = f2bf(W2[i]);
    if (i < 64 * 64)   w3b[i] = f2bf(W3[i]);
}

// ---------------- MFMA GEMM: C[M,N](bf16) = A[M,K](f32|bf16) @ Wb[K,N](bf16) ----------------

template<int K, int N, bool AF32>
__global__ __launch_bounds__(256)
void gemm_mfma(const void* __restrict__ Ap, const unsigned short* __restrict__ Wb,
               unsigned short* __restrict__ C, int M) {
    constexpr int KF = K / 32;
    constexpr int NF = N / 16;
    __shared__ __align__(16) unsigned short ldsW[KF * NF * 64 * 8];

    for (int c = threadIdx.x; c < K * N / 8; c += 256) {
        int e0 = c * 8;
        int k = e0 / N, n0 = e0 % N;
        uint4 v = *(const uint4*)&Wb[e0];
        unsigned short w[8];
        w[0] = (unsigned short)(v.x & 0xffff); w[1] = (unsigned short)(v.x >> 16);
        w[2] = (unsigned short)(v.y & 0xffff); w[3] = (unsigned short)(v.y >> 16);
        w[4] = (unsigned short)(v.z & 0xffff); w[5] = (unsigned short)(v.z >> 16);
        w[6] = (unsigned short)(v.w & 0xffff); w[7] = (unsigned short)(v.w >> 16);
        int j    = k & 7;
        int lhi  = ((k & 31) >> 3) << 4;
        int fbase = (k >> 5) * NF;
        #pragma unroll
        for (int u = 0; u < 8; ++u) {
            int n = n0 + u;
            int f = fbase + (n >> 4);
            int l = lhi | (n & 15);
            ldsW[(f * 64 + l) * 8 + j] = w[u];
        }
    }
    __syncthreads();

    const int wave = threadIdx.x >> 6;
    const int lane = threadIdx.x & 63;
    const int r0   = blockIdx.x * 64 + wave * 16;

    int arow = r0 + (lane & 15);
    if (arow >= M) arow = M - 1;
    const int kc0 = (lane >> 4) * 8;
    bf16x8 af[KF];
    #pragma unroll
    for (int k = 0; k < KF; ++k) {
        if constexpr (AF32) {
            const float* A = (const float*)Ap;
            const float4* p = (const float4*)&A[(size_t)arow * K + k * 32 + kc0];
            float4 u0 = p[0], u1 = p[1];
            unsigned int q0 = pack2bf(u0.x, u0.y), q1 = pack2bf(u0.z, u0.w);
            unsigned int q2 = pack2bf(u1.x, u1.y), q3 = pack2bf(u1.z, u1.w);
            bf16x8 a;
            a[0] = (short)(q0 & 0xffff); a[1] = (short)(q0 >> 16);
            a[2] = (short)(q1 & 0xffff); a[3] = (short)(q1 >> 16);
            a[4] = (short)(q2 & 0xffff); a[5] = (short)(q2 >> 16);
            a[6] = (short)(q3 & 0xffff); a[7] = (short)(q3 >> 16);
            af[k] = a;
        } else {
            const unsigned short* A = (const unsigned short*)Ap;
            af[k] = *(const bf16x8*)&A[(size_t)arow * K + k * 32 + kc0];
        }
    }

    const int colb = lane & 15;
    const int rsub = (lane >> 4) * 4;
    #pragma unroll
    for (int n = 0; n < NF; ++n) {
        f32x4 acc = {0.f, 0.f, 0.f, 0.f};
        #pragma unroll
        for (int k = 0; k < KF; ++k) {
            bf16x8 bf = *(const bf16x8*)&ldsW[((k * NF + n) * 64 + lane) * 8];
            acc = __builtin_amdgcn_mfma_f32_16x16x32_bf16(af[k], bf, acc, 0, 0, 0);
        }
        int col = n * 16 + colb;
        #pragma unroll
        for (int j = 0; j < 4; ++j) {
            int row = r0 + rsub + j;
            if (row < M) C[(size_t)row * N + col] = f2bf(acc[j]);
        }
    }
}

// ---------------- fused gather + self-loop + bias + BN + ReLU (bf16 in/out) ----------------

__global__ __launch_bounds__(256)
void gcn_gather128(const unsigned short* __restrict__ t, unsigned short* __restrict__ out,
                   const int* __restrict__ row_ptr, const int2* __restrict__ cw,
                   const float* __restrict__ dinv,
                   const float* __restrict__ bias,
                   const float* __restrict__ gam, const float* __restrict__ bet,
                   const float* __restrict__ mu,  const float* __restrict__ var,
                   int Nn) {
    int node = (int)((blockIdx.x * 256 + threadIdx.x) >> 6);
    int lane = threadIdx.x & 63;
    if (node >= Nn) return;

    int b0 = row_ptr[node];
    int b1 = row_ptr[node + 1];
    float di = dinv[node];
    const unsigned int* tu = (const unsigned int*)t;

    float acc0 = 0.0f, acc1 = 0.0f;
    int e = b0;
    for (; e + 16 <= b1; e += 16) {
        int2 c16[16];
        unsigned int f[16];
        #pragma unroll
        for (int u = 0; u < 16; ++u) c16[u] = cw[e + u];
        #pragma unroll
        for (int u = 0; u < 16; ++u) f[u] = tu[(size_t)c16[u].x * 64 + lane];
        #pragma unroll
        for (int u = 0; u < 16; ++u) {
            float w = __int_as_float(c16[u].y);
            acc0 = fmaf(w, bf2f((unsigned short)(f[u] & 0xffff)), acc0);
            acc1 = fmaf(w, bf2f((unsigned short)(f[u] >> 16)),   acc1);
        }
    }
    for (; e + 4 <= b1; e += 4) {
        int2 c4[4];
        unsigned int f[4];
        #pragma unroll
        for (int u = 0; u < 4; ++u) c4[u] = cw[e + u];
        #pragma unroll
        for (int u = 0; u < 4; ++u) f[u] = tu[(size_t)c4[u].x * 64 + lane];
        #pragma unroll
        for (int u = 0; u < 4; ++u) {
            float w = __int_as_float(c4[u].y);
            acc0 = fmaf(w, bf2f((unsigned short)(f[u] & 0xffff)), acc0);
            acc1 = fmaf(w, bf2f((unsigned short)(f[u] >> 16)),   acc1);
        }
    }
    for (; e < b1; ++e) {
        int2 c = cw[e];
        unsigned int f = tu[(size_t)c.x * 64 + lane];
        float w = __int_as_float(c.y);
        acc0 = fmaf(w, bf2f((unsigned short)(f & 0xffff)), acc0);
        acc1 = fmaf(w, bf2f((unsigned short)(f >> 16)),   acc1);
    }

    float d2 = di * di;
    unsigned int tv = tu[(size_t)node * 64 + lane];
    int c0 = 2 * lane, c1 = 2 * lane + 1;
    float sc0 = gam[c0] * rsqrtf(var[c0] + BN_EPS);
    float sc1 = gam[c1] * rsqrtf(var[c1] + BN_EPS);
    float sh0 = bet[c0] - mu[c0] * sc0;
    float sh1 = bet[c1] - mu[c1] * sc1;
    float h0 = di * acc0 + d2 * bf2f((unsigned short)(tv & 0xffff)) + bias[c0];
    float h1 = di * acc1 + d2 * bf2f((unsigned short)(tv >> 16))   + bias[c1];
    float o0 = fmaxf(h0 * sc0 + sh0, 0.0f);
    float o1 = fmaxf(h1 * sc1 + sh1, 0.0f);
    ((unsigned int*)out)[(size_t)node * 64 + lane] = pack2bf(o0, o1);
}

__global__ __launch_bounds__(256)
void gcn_gather64(const unsigned short* __restrict__ t, unsigned short* __restrict__ out,
                  const int* __restrict__ row_ptr, const int2* __restrict__ cw,
                  const float* __restrict__ dinv,
                  const float* __restrict__ bias,
                  const float* __restrict__ gam, const float* __restrict__ bet,
                  const float* __restrict__ mu,  const float* __restrict__ var,
                  int Nn) {
    int node = (int)((blockIdx.x * 256 + threadIdx.x) >> 6);
    int lane = threadIdx.x & 63;
    if (node >= Nn) return;

    int b0 = row_ptr[node];
    int b1 = row_ptr[node + 1];
    float di = dinv[node];

    float acc = 0.0f;
    int e = b0;
    for (; e + 16 <= b1; e += 16) {
        int2 c16[16];
        unsigned short f[16];
        #pragma unroll
        for (int u = 0; u < 16; ++u) c16[u] = cw[e + u];
        #pragma unroll
        for (int u = 0; u < 16; ++u) f[u] = t[(size_t)c16[u].x * 64 + lane];
        #pragma unroll
        for (int u = 0; u < 16; ++u)
            acc = fmaf(__int_as_float(c16[u].y), bf2f(f[u]), acc);
    }
    for (; e + 4 <= b1; e += 4) {
        int2 c4[4];
        unsigned short f[4];
        #pragma unroll
        for (int u = 0; u < 4; ++u) c4[u] = cw[e + u];
        #pragma unroll
        for (int u = 0; u < 4; ++u) f[u] = t[(size_t)c4[u].x * 64 + lane];
        #pragma unroll
        for (int u = 0; u < 4; ++u)
            acc = fmaf(__int_as_float(c4[u].y), bf2f(f[u]), acc);
    }
    for (; e < b1; ++e) {
        int2 c = cw[e];
        acc = fmaf(__int_as_float(c.y), bf2f(t[(size_t)c.x * 64 + lane]), acc);
    }

    float d2 = di * di;
    float tv = bf2f(t[(size_t)node * 64 + lane]);
    int c = lane;
    float sc = gam[c] * rsqrtf(var[c] + BN_EPS);
    float sh = bet[c] - mu[c] * sc;
    float h  = di * acc + d2 * tv + bias[c];
    out[(size_t)node * 64 + lane] = f2bf(fmaxf(h * sc + sh, 0.0f));
}

// ---------------- parallel pool: wave per 64-node chunk, lane = channel ----------------

__global__ __launch_bounds__(256)
void pool_sum_kernel(const unsigned short* __restrict__ h3, const int* __restrict__ batch,
                     float* __restrict__ sums, int Nn) {
    int wid  = (int)((blockIdx.x * 256 + threadIdx.x) >> 6);
    int lane = threadIdx.x & 63;
    int i0 = wid * 64;
    if (i0 >= Nn) return;
    int i1 = i0 + 64; if (i1 > Nn) i1 = Nn;

    float acc = 0.0f;
    int g = batch[i0];
    for (int i = i0; i < i1; ++i) {
        int gi = batch[i];
        if (gi != g) {
            unsafeAtomicAdd(&sums[g * 64 + lane], acc);
            acc = 0.0f;
            g = gi;
        }
        acc += bf2f(h3[(size_t)i * 64 + lane]);
    }
    unsafeAtomicAdd(&sums[g * 64 + lane], acc);
}

// ---------------- MLP head on pooled sums ----------------

__global__ __launch_bounds__(64)
void mlp_kernel(const float* __restrict__ sums, const int* __restrict__ start,
                const float* __restrict__ Wm1, const float* __restrict__ bm1,
                const float* __restrict__ Wm2, const float* __restrict__ bm2,
                float* __restrict__ out) {
    int g = blockIdx.x;
    int c = threadIdx.x;  // 64
    float cnt = (float)(start[g + 1] - start[g]);
    float pooled = sums[g * 64 + c] / fmaxf(cnt, 1.0f);
    __shared__ float pl[64];
    __shared__ float zl[64];
    pl[c] = pooled;
    __syncthreads();
    float z = bm1[c];
    for (int j = 0; j < 64; ++j) z = fmaf(pl[j], Wm1[j * 64 + c], z);
    z = fmaxf(z, 0.0f);
    zl[c] = z;
    __syncthreads();
    if (c < 10) {
        float o = bm2[c];
        for (int j = 0; j < 64; ++j) o = fmaf(zl[j], Wm2[j * 10 + c], o);
        out[g * 10 + c] = o;
    }
}

// ---------------- launcher ----------------

static inline int cdiv(int a, int b) { return (a + b - 1) / b; }

extern "C" void kernel_launch(void* const* d_in, const int* in_sizes, int n_in,
                              void* d_out, int out_size, void* d_ws, size_t ws_size,
                              hipStream_t stream) {
    const float* x   = (const float*)d_in[0];
    const int* edge  = (const int*)d_in[1];
    const int* batch = (const int*)d_in[2];
    const float* W1  = (const float*)d_in[3];
    const float* b1  = (const float*)d_in[4];
    const float* W2  = (const float*)d_in[5];
    const float* b2  = (const float*)d_in[6];
    const float* W3  = (const float*)d_in[7];
    const float* b3  = (const float*)d_in[8];
    const float* g1  = (const float*)d_in[9];
    const float* be1 = (const float*)d_in[10];
    const float* m1  = (const float*)d_in[11];
    const float* v1  = (const float*)d_in[12];
    const float* g2  = (const float*)d_in[13];
    const float* be2 = (const float*)d_in[14];
    const float* m2  = (const float*)d_in[15];
    const float* v2  = (const float*)d_in[16];
    const float* g3  = (const float*)d_in[17];
    const float* be3 = (const float*)d_in[18];
    const float* m3  = (const float*)d_in[19];
    const float* v3  = (const float*)d_in[20];
    const float* Wm1 = (const float*)d_in[21];
    const float* bm1 = (const float*)d_in[22];
    const float* Wm2 = (const float*)d_in[23];
    const float* bm2 = (const float*)d_in[24];
    float* outp = (float*)d_out;

    const int Nn = in_sizes[0] / 128;
    const int E  = in_sizes[1] / 2;
    const int G  = 128;
    const int* srcv = edge;
    const int* dstv = edge + E;

    // ws layout (bytes):
    // bufA (Nn*128 bf16) | bufB (Nn*128 bf16) | dinv (Nn f32) | cw (E int2) | bkt (E int2)
    // | row_ptr (Nn+1 int) | start (G+1 int) | sums (G*64 f32) | cursor(256) | w1b/w2b/w3b
    char* wsb = (char*)d_ws;
    unsigned short* bufA = (unsigned short*)wsb;
    unsigned short* bufB = bufA + (size_t)Nn * 128;
    float* dinv    = (float*)(bufB + (size_t)Nn * 128);
    int2*  cw      = (int2*)(dinv + Nn);
    int2*  bkt     = cw + E;
    int*   row_ptr = (int*)(bkt + E);
    int*   start   = row_ptr + (Nn + 1);
    float* sums    = (float*)(start + (G + 1));
    int*   cursor  = (int*)(sums + G * 64);
    unsigned short* w1b = (unsigned short*)(cursor + 256);
    unsigned short* w2b = w1b + 128 * 128;
    unsigned short* w3b = w2b + 128 * 64;

    // transient ints overlaid on bufA (free until GEMM1 writes it)
    int* cnt  = (int*)bufA;            // Nn
    int* bsum = cnt + Nn;              // cdiv(Nn,256)

    const int TB = 256;
    const int nb = cdiv(Nn, 256);
    const int nbkt = cdiv(Nn, 512);

    // ---- CSR build + norms + weight conversion + graph boundaries ----
    hipMemsetAsync(cnt, 0, (size_t)Nn * sizeof(int), stream);
    count_kernel<<<cdiv(E, TB), TB, 0, stream>>>(dstv, cnt, E);
    scan_block_kernel<<<nb, 256, 0, stream>>>(cnt, row_ptr, bsum, dinv, Nn);
    scan_sums_kernel<<<1, 512, 0, stream>>>(bsum, nb);
    add_offsets_kernel<<<nb, 256, 0, stream>>>(row_ptr, bsum, batch, start, Nn, E, G);
    cursor_init_kernel<<<1, 256, 0, stream>>>(row_ptr, cursor, Nn);
    bucketA_kernel<<<cdiv(E, 4096), 256, 0, stream>>>(srcv, dstv, dinv, cursor, bkt, E);
    orderB_kernel<<<nbkt, 256, 0, stream>>>(bkt, row_ptr, cw, Nn);
    convw_kernel<<<64, 256, 0, stream>>>(W1, W2, W3, w1b, w2b, w3b);

    // ---- layer 1: t = x @ W1 (128->128, f32 A -> bf16); gather -> bufB ----
    gemm_mfma<128, 128, true><<<cdiv(Nn, 64), 256, 0, stream>>>(x, w1b, bufA, Nn);
    gcn_gather128<<<cdiv(Nn, 4), 256, 0, stream>>>(bufA, bufB, row_ptr, cw, dinv,
                                                   b1, g1, be1, m1, v1, Nn);

    // ---- layer 2: t = h1 @ W2 (128->64) ----
    gemm_mfma<128, 64, false><<<cdiv(Nn, 64), 256, 0, stream>>>(bufB, w2b, bufA, Nn);
    gcn_gather64<<<cdiv(Nn, 4), 256, 0, stream>>>(bufA, bufB, row_ptr, cw, dinv,
                                                  b2, g2, be2, m2, v2, Nn);

    // ---- layer 3: t = h2 @ W3 (64->64) ----
    gemm_mfma<64, 64, false><<<cdiv(Nn, 64), 256, 0, stream>>>(bufB, w3b, bufA, Nn);
    gcn_gather64<<<cdiv(Nn, 4), 256, 0, stream>>>(bufA, bufB, row_ptr, cw, dinv,
                                                  b3, g3, be3, m3, v3, Nn);

    // ---- pool + MLP ----
    hipMemsetAsync(sums, 0, (size_t)G * 64 * sizeof(float), stream);
    pool_sum_kernel<<<cdiv(Nn, 256), 256, 0, stream>>>(bufB, batch, sums, Nn);
    mlp_kernel<<<G, 64, 0, stream>>>(sums, start, Wm1, bm1, Wm2, bm2, outp);
}

// Round 14
// 352.516 us; speedup vs baseline: 1.3479x; 1.2467x over previous
//
#include <hip/hip_runtime.h>
#include <math.h>

#define BN_EPS 1e-5f

using bf16x8 = __attribute__((ext_vector_type(8))) short;
using f32x4  = __attribute__((ext_vector_type(4))) float;

// ---------------- bf16 helpers (RNE) ----------------

__device__ __forceinline__ float bf2f(unsigned short u) {
    union { unsigned int i; float f; } v; v.i = ((unsigned int)u) << 16; return v.f;
}
__device__ __forceinline__ unsigned short f2bf(float f) {
    union { float f; unsigned int i; } v; v.f = f;
    unsigned int lsb = (v.i >> 16) & 1u;
    v.i += 0x7fffu + lsb;
    return (unsigned short)(v.i >> 16);
}
__device__ __forceinline__ unsigned int pack2bf(float a, float b) {
    return (unsigned int)f2bf(a) | ((unsigned int)f2bf(b) << 16);
}

// ---------------- CSR build (hierarchical, no per-node global atomics) ----------------
// buckets: 512 dst nodes each, b = d>>9 (<=256 buckets)

__global__ __launch_bounds__(256)
void coarse_count_kernel(const int* __restrict__ dstv, int* __restrict__ bucketCnt, int E) {
    __shared__ int hist[256];
    int tid = threadIdx.x;
    hist[tid] = 0;
    __syncthreads();
    int e0 = blockIdx.x * 4096;
    int nmax = E - e0; if (nmax > 4096) nmax = 4096;
    #pragma unroll
    for (int u = 0; u < 16; ++u) {
        int idx = u * 256 + tid;
        if (idx < nmax) atomicAdd(&hist[dstv[e0 + idx] >> 9], 1);
    }
    __syncthreads();
    if (hist[tid] > 0) atomicAdd(&bucketCnt[tid], hist[tid]);
}

// 1 block: exclusive scan of bucketCnt -> bucketBase & cursor; row_ptr[Nn]=E
__global__ void scanB_kernel(const int* __restrict__ bucketCnt, int* __restrict__ bucketBase,
                             int* __restrict__ cursor, int* __restrict__ row_ptr, int E, int Nn) {
    __shared__ int s[256];
    int t = threadIdx.x;
    int v = bucketCnt[t];
    s[t] = v;
    __syncthreads();
    for (int off = 1; off < 256; off <<= 1) {
        int add = (t >= off) ? s[t - off] : 0;
        __syncthreads();
        s[t] += add;
        __syncthreads();
    }
    int excl = s[t] - v;
    bucketBase[t] = excl;
    cursor[t] = excl;
    if (t == 0) row_ptr[Nn] = E;
}

// Phase A: append packed (src | dstLocal<<17) into bucket regions (block-contiguous bursts)
__global__ __launch_bounds__(256)
void bucketA_kernel(const int* __restrict__ srcv, const int* __restrict__ dstv,
                    int* __restrict__ cursor, int* __restrict__ bkt, int E) {
    __shared__ int hist[256], base[256], lcur[256];
    __shared__ int2 stage[4096];
    int tid = threadIdx.x;
    hist[tid] = 0; lcur[tid] = 0;
    __syncthreads();
    int e0 = blockIdx.x * 4096;
    int nmax = E - e0; if (nmax > 4096) nmax = 4096;

    #pragma unroll
    for (int u = 0; u < 16; ++u) {
        int idx = u * 256 + tid;
        if (idx < nmax) {
            int e = e0 + idx;
            int d = dstv[e], s = srcv[e];
            stage[idx] = make_int2(d, s);
            atomicAdd(&hist[d >> 9], 1);
        }
    }
    __syncthreads();
    if (hist[tid] > 0) base[tid] = atomicAdd(&cursor[tid], hist[tid]);
    __syncthreads();
    #pragma unroll
    for (int u = 0; u < 16; ++u) {
        int idx = u * 256 + tid;
        if (idx < nmax) {
            int2 ds = stage[idx];
            int b = ds.x >> 9;
            int dl = ds.x & 511;
            int slot = atomicAdd(&lcur[b], 1);
            bkt[base[b] + slot] = ds.y | (dl << 17);
        }
    }
}

// Phase B: one block per bucket — per-node degree/dinv/row_ptr in LDS, reorder col
// in block-local window; also graph boundaries (batch sorted).
__global__ __launch_bounds__(256)
void orderB_kernel(const int* __restrict__ bkt, const int* __restrict__ bucketBase,
                   int* __restrict__ row_ptr, float* __restrict__ dinv, int* __restrict__ col,
                   const int* __restrict__ batch, int* __restrict__ start,
                   int Nn, int E, int G) {
    __shared__ int hist[512];
    __shared__ int scan_s[256];
    int b = blockIdx.x;
    int lo = b << 9;
    if (lo >= Nn) return;
    int hi = lo + 512; if (hi > Nn) hi = Nn;
    int s0 = bucketBase[b];
    int s1 = (b == 255) ? E : bucketBase[b + 1];
    int tid = threadIdx.x;
    hist[tid] = 0; hist[tid + 256] = 0;
    __syncthreads();
    for (int i = s0 + tid; i < s1; i += 256)
        atomicAdd(&hist[(((unsigned int)bkt[i]) >> 17) & 511], 1);
    __syncthreads();
    int a0 = hist[2 * tid], a1 = hist[2 * tid + 1];
    int n0 = lo + 2 * tid, n1 = n0 + 1;
    if (n0 < Nn) dinv[n0] = rsqrtf((float)a0 + 1.0f);
    if (n1 < Nn) dinv[n1] = rsqrtf((float)a1 + 1.0f);
    int pairsum = a0 + a1;
    scan_s[tid] = pairsum;
    __syncthreads();
    for (int off = 1; off < 256; off <<= 1) {
        int add = (tid >= off) ? scan_s[tid - off] : 0;
        __syncthreads();
        scan_s[tid] += add;
        __syncthreads();
    }
    int excl = scan_s[tid] - pairsum;
    __syncthreads();
    if (n0 < Nn) row_ptr[n0] = s0 + excl;
    if (n1 < Nn) row_ptr[n1] = s0 + excl + a0;
    hist[2 * tid] = excl;
    hist[2 * tid + 1] = excl + a0;
    __syncthreads();
    for (int i = s0 + tid; i < s1; i += 256) {
        int en = bkt[i];
        int dl = (((unsigned int)en) >> 17) & 511;
        int slot = atomicAdd(&hist[dl], 1);
        col[s0 + slot] = en & 0x1ffff;
    }
    // graph boundaries for this node range
    for (int i = lo + tid; i < hi; i += 256) {
        int bb = batch[i];
        if (i == 0) {
            for (int g = 0; g <= bb; ++g) start[g] = 0;
        } else {
            int p = batch[i - 1];
            for (int g = p + 1; g <= bb; ++g) start[g] = i;
        }
        if (i == Nn - 1) {
            for (int g = bb + 1; g <= G; ++g) start[g] = Nn;
        }
    }
}

// ---------------- weight f32 -> bf16 conversion ----------------

__global__ void convw_kernel(const float* __restrict__ W1, const float* __restrict__ W2,
                             const float* __restrict__ W3,
                             unsigned short* __restrict__ w1b, unsigned short* __restrict__ w2b,
                             unsigned short* __restrict__ w3b) {
    int i = blockIdx.x * 256 + threadIdx.x;
    if (i < 128 * 128) w1b[i] = f2bf(W1[i]);
    if (i < 128 * 64)  w2b[i] = f2bf(W2[i]);
    if (i < 64 * 64)   w3b[i] = f2bf(W3[i]);
}

// ---------------- MFMA GEMM: C[M,N](bf16) = dinv[row] * (A[M,K] @ Wb[K,N]) ----------------
// (scaled epilogue: C is the pre-scaled message t' = dinv * (A@W))

template<int K, int N, bool AF32>
__global__ __launch_bounds__(256)
void gemm_mfma(const void* __restrict__ Ap, const unsigned short* __restrict__ Wb,
               const float* __restrict__ dinv, unsigned short* __restrict__ C, int M) {
    constexpr int KF = K / 32;
    constexpr int NF = N / 16;
    __shared__ __align__(16) unsigned short ldsW[KF * NF * 64 * 8];

    for (int c = threadIdx.x; c < K * N / 8; c += 256) {
        int e0 = c * 8;
        int k = e0 / N, n0 = e0 % N;
        uint4 v = *(const uint4*)&Wb[e0];
        unsigned short w[8];
        w[0] = (unsigned short)(v.x & 0xffff); w[1] = (unsigned short)(v.x >> 16);
        w[2] = (unsigned short)(v.y & 0xffff); w[3] = (unsigned short)(v.y >> 16);
        w[4] = (unsigned short)(v.z & 0xffff); w[5] = (unsigned short)(v.z >> 16);
        w[6] = (unsigned short)(v.w & 0xffff); w[7] = (unsigned short)(v.w >> 16);
        int j    = k & 7;
        int lhi  = ((k & 31) >> 3) << 4;
        int fbase = (k >> 5) * NF;
        #pragma unroll
        for (int u = 0; u < 8; ++u) {
            int n = n0 + u;
            int f = fbase + (n >> 4);
            int l = lhi | (n & 15);
            ldsW[(f * 64 + l) * 8 + j] = w[u];
        }
    }
    __syncthreads();

    const int wave = threadIdx.x >> 6;
    const int lane = threadIdx.x & 63;
    const int r0   = blockIdx.x * 64 + wave * 16;

    int arow = r0 + (lane & 15);
    if (arow >= M) arow = M - 1;
    const int kc0 = (lane >> 4) * 8;
    bf16x8 af[KF];
    #pragma unroll
    for (int k = 0; k < KF; ++k) {
        if constexpr (AF32) {
            const float* A = (const float*)Ap;
            const float4* p = (const float4*)&A[(size_t)arow * K + k * 32 + kc0];
            float4 u0 = p[0], u1 = p[1];
            unsigned int q0 = pack2bf(u0.x, u0.y), q1 = pack2bf(u0.z, u0.w);
            unsigned int q2 = pack2bf(u1.x, u1.y), q3 = pack2bf(u1.z, u1.w);
            bf16x8 a;
            a[0] = (short)(q0 & 0xffff); a[1] = (short)(q0 >> 16);
            a[2] = (short)(q1 & 0xffff); a[3] = (short)(q1 >> 16);
            a[4] = (short)(q2 & 0xffff); a[5] = (short)(q2 >> 16);
            a[6] = (short)(q3 & 0xffff); a[7] = (short)(q3 >> 16);
            af[k] = a;
        } else {
            const unsigned short* A = (const unsigned short*)Ap;
            af[k] = *(const bf16x8*)&A[(size_t)arow * K + k * 32 + kc0];
        }
    }

    const int colb = lane & 15;
    const int rsub = (lane >> 4) * 4;
    float dv[4];
    #pragma unroll
    for (int j = 0; j < 4; ++j) {
        int row = r0 + rsub + j;
        dv[j] = (row < M) ? dinv[row] : 0.0f;
    }
    #pragma unroll
    for (int n = 0; n < NF; ++n) {
        f32x4 acc = {0.f, 0.f, 0.f, 0.f};
        #pragma unroll
        for (int k = 0; k < KF; ++k) {
            bf16x8 bf = *(const bf16x8*)&ldsW[((k * NF + n) * 64 + lane) * 8];
            acc = __builtin_amdgcn_mfma_f32_16x16x32_bf16(af[k], bf, acc, 0, 0, 0);
        }
        int col = n * 16 + colb;
        #pragma unroll
        for (int j = 0; j < 4; ++j) {
            int row = r0 + rsub + j;
            if (row < M) C[(size_t)row * N + col] = f2bf(acc[j] * dv[j]);
        }
    }
}

// ---------------- fused gather + bias + BN + ReLU (bf16 in/out, pre-scaled t') ----------------
// out[i] = relu(BN( dinv[i] * (sum_{s in N(i)} t'[s] + t'[i]) + bias ))

__global__ __launch_bounds__(256)
void gcn_gather128(const unsigned short* __restrict__ t, unsigned short* __restrict__ out,
                   const int* __restrict__ row_ptr, const int* __restrict__ col,
                   const float* __restrict__ dinv,
                   const float* __restrict__ bias,
                   const float* __restrict__ gam, const float* __restrict__ bet,
                   const float* __restrict__ mu,  const float* __restrict__ var,
                   int Nn) {
    int node = (int)((blockIdx.x * 256 + threadIdx.x) >> 6);
    int lane = threadIdx.x & 63;
    if (node >= Nn) return;

    int b0 = row_ptr[node];
    int b1 = row_ptr[node + 1];
    float di = dinv[node];
    const unsigned int* tu = (const unsigned int*)t;

    float acc0 = 0.0f, acc1 = 0.0f;
    int e = b0;
    for (; e + 16 <= b1; e += 16) {
        int c16[16];
        unsigned int f[16];
        #pragma unroll
        for (int u = 0; u < 16; ++u) c16[u] = col[e + u];
        #pragma unroll
        for (int u = 0; u < 16; ++u) f[u] = tu[(size_t)c16[u] * 64 + lane];
        #pragma unroll
        for (int u = 0; u < 16; ++u) {
            acc0 += bf2f((unsigned short)(f[u] & 0xffff));
            acc1 += bf2f((unsigned short)(f[u] >> 16));
        }
    }
    for (; e + 4 <= b1; e += 4) {
        int c4[4];
        unsigned int f[4];
        #pragma unroll
        for (int u = 0; u < 4; ++u) c4[u] = col[e + u];
        #pragma unroll
        for (int u = 0; u < 4; ++u) f[u] = tu[(size_t)c4[u] * 64 + lane];
        #pragma unroll
        for (int u = 0; u < 4; ++u) {
            acc0 += bf2f((unsigned short)(f[u] & 0xffff));
            acc1 += bf2f((unsigned short)(f[u] >> 16));
        }
    }
    for (; e < b1; ++e) {
        unsigned int f = tu[(size_t)col[e] * 64 + lane];
        acc0 += bf2f((unsigned short)(f & 0xffff));
        acc1 += bf2f((unsigned short)(f >> 16));
    }

    // self-loop: + t'[node]
    unsigned int tv = tu[(size_t)node * 64 + lane];
    acc0 += bf2f((unsigned short)(tv & 0xffff));
    acc1 += bf2f((unsigned short)(tv >> 16));

    int c0 = 2 * lane, c1 = 2 * lane + 1;
    float sc0 = gam[c0] * rsqrtf(var[c0] + BN_EPS);
    float sc1 = gam[c1] * rsqrtf(var[c1] + BN_EPS);
    float sh0 = bet[c0] - mu[c0] * sc0;
    float sh1 = bet[c1] - mu[c1] * sc1;
    float h0 = di * acc0 + bias[c0];
    float h1 = di * acc1 + bias[c1];
    float o0 = fmaxf(h0 * sc0 + sh0, 0.0f);
    float o1 = fmaxf(h1 * sc1 + sh1, 0.0f);
    ((unsigned int*)out)[(size_t)node * 64 + lane] = pack2bf(o0, o1);
}

__global__ __launch_bounds__(256)
void gcn_gather64(const unsigned short* __restrict__ t, unsigned short* __restrict__ out,
                  const int* __restrict__ row_ptr, const int* __restrict__ col,
                  const float* __restrict__ dinv,
                  const float* __restrict__ bias,
                  const float* __restrict__ gam, const float* __restrict__ bet,
                  const float* __restrict__ mu,  const float* __restrict__ var,
                  int Nn) {
    int node = (int)((blockIdx.x * 256 + threadIdx.x) >> 6);
    int lane = threadIdx.x & 63;
    if (node >= Nn) return;

    int b0 = row_ptr[node];
    int b1 = row_ptr[node + 1];
    float di = dinv[node];

    float acc = 0.0f;
    int e = b0;
    for (; e + 16 <= b1; e += 16) {
        int c16[16];
        unsigned short f[16];
        #pragma unroll
        for (int u = 0; u < 16; ++u) c16[u] = col[e + u];
        #pragma unroll
        for (int u = 0; u < 16; ++u) f[u] = t[(size_t)c16[u] * 64 + lane];
        #pragma unroll
        for (int u = 0; u < 16; ++u) acc += bf2f(f[u]);
    }
    for (; e + 4 <= b1; e += 4) {
        int c4[4];
        unsigned short f[4];
        #pragma unroll
        for (int u = 0; u < 4; ++u) c4[u] = col[e + u];
        #pragma unroll
        for (int u = 0; u < 4; ++u) f[u] = t[(size_t)c4[u] * 64 + lane];
        #pragma unroll
        for (int u = 0; u < 4; ++u) acc += bf2f(f[u]);
    }
    for (; e < b1; ++e) acc += bf2f(t[(size_t)col[e] * 64 + lane]);

    acc += bf2f(t[(size_t)node * 64 + lane]);  // self-loop

    int c = lane;
    float sc = gam[c] * rsqrtf(var[c] + BN_EPS);
    float sh = bet[c] - mu[c] * sc;
    float h  = di * acc + bias[c];
    out[(size_t)node * 64 + lane] = f2bf(fmaxf(h * sc + sh, 0.0f));
}

// ---------------- parallel pool: wave per 64-node chunk, lane = channel ----------------

__global__ __launch_bounds__(256)
void pool_sum_kernel(const unsigned short* __restrict__ h3, const int* __restrict__ batch,
                     float* __restrict__ sums, int Nn) {
    int wid  = (int)((blockIdx.x * 256 + threadIdx.x) >> 6);
    int lane = threadIdx.x & 63;
    int i0 = wid * 64;
    if (i0 >= Nn) return;
    int i1 = i0 + 64; if (i1 > Nn) i1 = Nn;

    float acc = 0.0f;
    int g = batch[i0];
    for (int i = i0; i < i1; ++i) {
        int gi = batch[i];
        if (gi != g) {
            unsafeAtomicAdd(&sums[g * 64 + lane], acc);
            acc = 0.0f;
            g = gi;
        }
        acc += bf2f(h3[(size_t)i * 64 + lane]);
    }
    unsafeAtomicAdd(&sums[g * 64 + lane], acc);
}

// ---------------- MLP head on pooled sums ----------------

__global__ __launch_bounds__(64)
void mlp_kernel(const float* __restrict__ sums, const int* __restrict__ start,
                const float* __restrict__ Wm1, const float* __restrict__ bm1,
                const float* __restrict__ Wm2, const float* __restrict__ bm2,
                float* __restrict__ out) {
    int g = blockIdx.x;
    int c = threadIdx.x;  // 64
    float cnt = (float)(start[g + 1] - start[g]);
    float pooled = sums[g * 64 + c] / fmaxf(cnt, 1.0f);
    __shared__ float pl[64];
    __shared__ float zl[64];
    pl[c] = pooled;
    __syncthreads();
    float z = bm1[c];
    for (int j = 0; j < 64; ++j) z = fmaf(pl[j], Wm1[j * 64 + c], z);
    z = fmaxf(z, 0.0f);
    zl[c] = z;
    __syncthreads();
    if (c < 10) {
        float o = bm2[c];
        for (int j = 0; j < 64; ++j) o = fmaf(zl[j], Wm2[j * 10 + c], o);
        out[g * 10 + c] = o;
    }
}

// ---------------- launcher ----------------

static inline int cdiv(int a, int b) { return (a + b - 1) / b; }

extern "C" void kernel_launch(void* const* d_in, const int* in_sizes, int n_in,
                              void* d_out, int out_size, void* d_ws, size_t ws_size,
                              hipStream_t stream) {
    const float* x   = (const float*)d_in[0];
    const int* edge  = (const int*)d_in[1];
    const int* batch = (const int*)d_in[2];
    const float* W1  = (const float*)d_in[3];
    const float* b1  = (const float*)d_in[4];
    const float* W2  = (const float*)d_in[5];
    const float* b2  = (const float*)d_in[6];
    const float* W3  = (const float*)d_in[7];
    const float* b3  = (const float*)d_in[8];
    const float* g1  = (const float*)d_in[9];
    const float* be1 = (const float*)d_in[10];
    const float* m1  = (const float*)d_in[11];
    const float* v1  = (const float*)d_in[12];
    const float* g2  = (const float*)d_in[13];
    const float* be2 = (const float*)d_in[14];
    const float* m2  = (const float*)d_in[15];
    const float* v2  = (const float*)d_in[16];
    const float* g3  = (const float*)d_in[17];
    const float* be3 = (const float*)d_in[18];
    const float* m3  = (const float*)d_in[19];
    const float* v3  = (const float*)d_in[20];
    const float* Wm1 = (const float*)d_in[21];
    const float* bm1 = (const float*)d_in[22];
    const float* Wm2 = (const float*)d_in[23];
    const float* bm2 = (const float*)d_in[24];
    float* outp = (float*)d_out;

    const int Nn = in_sizes[0] / 128;
    const int E  = in_sizes[1] / 2;
    const int G  = 128;
    const int* srcv = edge;
    const int* dstv = edge + E;

    // ws layout (bytes):
    // bufA (Nn*128 bf16) | bufB (Nn*128 bf16) | dinv (Nn f32) | col (E int) | bkt (E int)
    // | row_ptr (Nn+1) | start (G+1) | sums (G*64 f32) | bucketCnt(256) | bucketBase(256)
    // | cursor(256) | w1b/w2b/w3b
    char* wsb = (char*)d_ws;
    unsigned short* bufA = (unsigned short*)wsb;
    unsigned short* bufB = bufA + (size_t)Nn * 128;
    float* dinv    = (float*)(bufB + (size_t)Nn * 128);
    int*   col     = (int*)(dinv + Nn);
    int*   bkt     = col + E;
    int*   row_ptr = bkt + E;
    int*   start   = row_ptr + (Nn + 1);
    float* sums    = (float*)(start + (G + 1));
    int*   bucketCnt  = (int*)(sums + G * 64);
    int*   bucketBase = bucketCnt + 256;
    int*   cursor     = bucketBase + 256;
    unsigned short* w1b = (unsigned short*)(cursor + 256);
    unsigned short* w2b = w1b + 128 * 128;
    unsigned short* w3b = w2b + 128 * 64;

    const int nbkt = cdiv(Nn, 512);

    // ---- CSR build (hierarchical) + weight conversion ----
    hipMemsetAsync(bucketCnt, 0, 256 * sizeof(int), stream);
    coarse_count_kernel<<<cdiv(E, 4096), 256, 0, stream>>>(dstv, bucketCnt, E);
    scanB_kernel<<<1, 256, 0, stream>>>(bucketCnt, bucketBase, cursor, row_ptr, E, Nn);
    bucketA_kernel<<<cdiv(E, 4096), 256, 0, stream>>>(srcv, dstv, cursor, bkt, E);
    orderB_kernel<<<nbkt, 256, 0, stream>>>(bkt, bucketBase, row_ptr, dinv, col,
                                            batch, start, Nn, E, G);
    convw_kernel<<<64, 256, 0, stream>>>(W1, W2, W3, w1b, w2b, w3b);

    // ---- layer 1: t' = dinv*(x @ W1); gather -> bufB ----
    gemm_mfma<128, 128, true><<<cdiv(Nn, 64), 256, 0, stream>>>(x, w1b, dinv, bufA, Nn);
    gcn_gather128<<<cdiv(Nn, 4), 256, 0, stream>>>(bufA, bufB, row_ptr, col, dinv,
                                                   b1, g1, be1, m1, v1, Nn);

    // ---- layer 2 ----
    gemm_mfma<128, 64, false><<<cdiv(Nn, 64), 256, 0, stream>>>(bufB, w2b, dinv, bufA, Nn);
    gcn_gather64<<<cdiv(Nn, 4), 256, 0, stream>>>(bufA, bufB, row_ptr, col, dinv,
                                                  b2, g2, be2, m2, v2, Nn);

    // ---- layer 3 ----
    gemm_mfma<64, 64, false><<<cdiv(Nn, 64), 256, 0, stream>>>(bufB, w3b, dinv, bufA, Nn);
    gcn_gather64<<<cdiv(Nn, 4), 256, 0, stream>>>(bufA, bufB, row_ptr, col, dinv,
                                                  b3, g3, be3, m3, v3, Nn);

    // ---- pool + MLP ----
    hipMemsetAsync(sums, 0, (size_t)G * 64 * sizeof(float), stream);
    pool_sum_kernel<<<cdiv(Nn, 256), 256, 0, stream>>>(bufB, batch, sums, Nn);
    mlp_kernel<<<G, 64, 0, stream>>>(sums, start, Wm1, bm1, Wm2, bm2, outp);
}